// Round 1
// baseline (1126.622 us; speedup 1.0000x reference)
//
#include <hip/hip_runtime.h>

#define N_NODES 50000
#define N_EDGES 800000
#define LN_EPS 1e-5f

// ---- combine global edge transform with per-layer edge weight: Wc = We @ eW, bc = be @ eW + eb ----
__global__ void wcomb_kernel(const float* __restrict__ We, const float* __restrict__ be,
                             const float* __restrict__ eW, const float* __restrict__ eb,
                             float* __restrict__ Wc, float* __restrict__ bc) {
  int tid = threadIdx.x; // 256 threads
  for (int idx = tid; idx < 64 * 64; idx += 256) {
    int k = idx >> 6, c = idx & 63;
    float s = 0.f;
    for (int j = 0; j < 64; ++j) s = fmaf(We[k * 64 + j], eW[j * 64 + c], s);
    Wc[idx] = s;
  }
  if (tid < 64) {
    float s = eb[tid];
    for (int j = 0; j < 64; ++j) s = fmaf(be[j], eW[j * 64 + tid], s);
    bc[tid] = s;
  }
}

__global__ void deg_kernel(const int* __restrict__ col, float* __restrict__ deg) {
  int e = blockIdx.x * blockDim.x + threadIdx.x;
  if (e < N_EDGES) atomicAdd(&deg[col[e]], 1.0f);
}

__global__ void dis_kernel(float* deg) {
  int n = blockIdx.x * blockDim.x + threadIdx.x;
  if (n < N_NODES) { float d = deg[n]; deg[n] = d > 0.f ? rsqrtf(d) : 0.f; }
}

__global__ void norm_kernel(const int* __restrict__ row, const int* __restrict__ col,
                            const float* __restrict__ dis, float* __restrict__ nrm) {
  int e = blockIdx.x * blockDim.x + threadIdx.x;
  if (e < N_EDGES) nrm[e] = dis[row[e]] * dis[col[e]];
}

// ---- node GEMM: Y[N,64] = X[N,K] @ W[K,64] + B. lane = row; W row via uniform s_load. ----
template <int K>
__global__ __launch_bounds__(64) void node_gemm_kernel(
    const float* __restrict__ X, const float* __restrict__ W, const float* __restrict__ B,
    float* __restrict__ Y) {
  int lane = threadIdx.x;
  int row = blockIdx.x * 64 + lane;
  int r = row < N_NODES ? row : N_NODES - 1;
  const float* xr = X + (long)r * K;
  float acc[64];
#pragma unroll
  for (int c = 0; c < 64; ++c) acc[c] = B[c];
#pragma unroll 1
  for (int kb = 0; kb < K; kb += 8) {
    float4 a0 = *(const float4*)(xr + kb);
    float4 a1 = *(const float4*)(xr + kb + 4);
    float av[8] = {a0.x, a0.y, a0.z, a0.w, a1.x, a1.y, a1.z, a1.w};
#pragma unroll
    for (int kk = 0; kk < 8; ++kk) {
      const float* wr = W + (kb + kk) * 64;
#pragma unroll
      for (int c = 0; c < 64; ++c) acc[c] = fmaf(av[kk], wr[c], acc[c]);
    }
  }
  if (row < N_NODES) {
    float* yr = Y + (long)row * 64;
#pragma unroll
    for (int c = 0; c < 64; c += 4) {
      float4 v = {acc[c], acc[c + 1], acc[c + 2], acc[c + 3]};
      *(float4*)(yr + c) = v;
    }
  }
}

// ---- fused edge kernel: per 64-edge tile: efl = attr @ Wc + bc (lane=edge, W via s_load),
//      transpose through padded LDS, then per-edge coalesced gather+atomic scatter (lane=channel) ----
__global__ __launch_bounds__(64) void edge_layer_kernel(
    const float* __restrict__ attr, const int* __restrict__ rowI, const int* __restrict__ colI,
    const float* __restrict__ nrm, const float* __restrict__ Wc, const float* __restrict__ bc,
    const float* __restrict__ XL, float* __restrict__ OUT) {
  __shared__ float efl[64][65];
  int lane = threadIdx.x;
  long e0 = (long)blockIdx.x * 64;
  const float* arow = attr + (e0 + lane) * 64;
  float acc[64];
#pragma unroll
  for (int c = 0; c < 64; ++c) acc[c] = bc[c];
#pragma unroll 1
  for (int kb = 0; kb < 64; kb += 8) {
    float4 a0 = *(const float4*)(arow + kb);
    float4 a1 = *(const float4*)(arow + kb + 4);
    float av[8] = {a0.x, a0.y, a0.z, a0.w, a1.x, a1.y, a1.z, a1.w};
#pragma unroll
    for (int kk = 0; kk < 8; ++kk) {
      const float* wr = Wc + (kb + kk) * 64;
#pragma unroll
      for (int c = 0; c < 64; ++c) acc[c] = fmaf(av[kk], wr[c], acc[c]);
    }
  }
#pragma unroll
  for (int c = 0; c < 64; c += 4) {
    float4 v = {acc[c], acc[c + 1], acc[c + 2], acc[c + 3]};
    *(float4*)&efl[lane][c] = v;
  }
  __syncthreads();
#pragma unroll 4
  for (int i = 0; i < 64; ++i) {
    int r = rowI[e0 + i];    // wave-uniform -> s_load
    int cl = colI[e0 + i];
    float nm = nrm[e0 + i];
    float v = nm * efl[i][lane] * XL[(long)r * 64 + lane];
    atomicAdd(&OUT[(long)cl * 64 + lane], v);
  }
}

// ---- fused ReLU + LayerNorm over rows of 64; one wave per row ----
__global__ void relu_ln_kernel(float* __restrict__ H, const float* __restrict__ G,
                               const float* __restrict__ B) {
  int t = blockIdx.x * blockDim.x + threadIdx.x;
  int row = t >> 6, lane = t & 63;
  if (row >= N_NODES) return;
  float v = H[(long)row * 64 + lane];
  v = fmaxf(v, 0.f);
  float s = v;
#pragma unroll
  for (int off = 32; off > 0; off >>= 1) s += __shfl_xor(s, off);
  float mu = s * (1.f / 64.f);
  float d = v - mu;
  float q = d * d;
#pragma unroll
  for (int off = 32; off > 0; off >>= 1) q += __shfl_xor(q, off);
  float var = q * (1.f / 64.f);
  H[(long)row * 64 + lane] = d * rsqrtf(var + LN_EPS) * G[lane] + B[lane];
}

extern "C" void kernel_launch(void* const* d_in, const int* in_sizes, int n_in,
                              void* d_out, int out_size, void* d_ws, size_t ws_size,
                              hipStream_t stream) {
  const float* x   = (const float*)d_in[0];
  const int* eidx  = (const int*)d_in[1];
  const float* attr = (const float*)d_in[2];
  const float* We  = (const float*)d_in[3];
  const float* be  = (const float*)d_in[4];
  const float* W0  = (const float*)d_in[5];  const float* b0  = (const float*)d_in[6];
  const float* eW0 = (const float*)d_in[7];  const float* eb0 = (const float*)d_in[8];
  const float* W1  = (const float*)d_in[9];  const float* b1  = (const float*)d_in[10];
  const float* eW1 = (const float*)d_in[11]; const float* eb1 = (const float*)d_in[12];
  const float* W2  = (const float*)d_in[13]; const float* b2  = (const float*)d_in[14];
  const float* eW2 = (const float*)d_in[15]; const float* eb2 = (const float*)d_in[16];
  const float* g0  = (const float*)d_in[17]; const float* bt0 = (const float*)d_in[18];
  const float* g1  = (const float*)d_in[19]; const float* bt1 = (const float*)d_in[20];
  const int* rowI = eidx;
  const int* colI = eidx + N_EDGES;
  float* out = (float*)d_out;

  char* ws = (char*)d_ws;
  float* xl  = (float*)ws; ws += (size_t)N_NODES * 64 * 4;
  float* hA  = (float*)ws; ws += (size_t)N_NODES * 64 * 4;
  float* nrm = (float*)ws; ws += (size_t)N_EDGES * 4;
  float* dis = (float*)ws; ws += (size_t)N_NODES * 4;
  float* Wc  = (float*)ws; ws += 3 * 64 * 64 * 4;
  float* bc  = (float*)ws; ws += 3 * 64 * 4;

  hipMemsetAsync(dis, 0, (size_t)N_NODES * 4, stream);
  deg_kernel<<<(N_EDGES + 255) / 256, 256, 0, stream>>>(colI, dis);
  dis_kernel<<<(N_NODES + 255) / 256, 256, 0, stream>>>(dis);
  norm_kernel<<<(N_EDGES + 255) / 256, 256, 0, stream>>>(rowI, colI, dis, nrm);
  wcomb_kernel<<<1, 256, 0, stream>>>(We, be, eW0, eb0, Wc,        bc);
  wcomb_kernel<<<1, 256, 0, stream>>>(We, be, eW1, eb1, Wc + 4096, bc + 64);
  wcomb_kernel<<<1, 256, 0, stream>>>(We, be, eW2, eb2, Wc + 8192, bc + 128);

  // layer 0
  node_gemm_kernel<128><<<(N_NODES + 63) / 64, 64, 0, stream>>>(x, W0, b0, xl);
  hipMemsetAsync(hA, 0, (size_t)N_NODES * 64 * 4, stream);
  edge_layer_kernel<<<N_EDGES / 64, 64, 0, stream>>>(attr, rowI, colI, nrm, Wc, bc, xl, hA);
  relu_ln_kernel<<<(N_NODES * 64 + 255) / 256, 256, 0, stream>>>(hA, g0, bt0);
  // layer 1
  node_gemm_kernel<64><<<(N_NODES + 63) / 64, 64, 0, stream>>>(hA, W1, b1, xl);
  hipMemsetAsync(hA, 0, (size_t)N_NODES * 64 * 4, stream);
  edge_layer_kernel<<<N_EDGES / 64, 64, 0, stream>>>(attr, rowI, colI, nrm, Wc + 4096, bc + 64, xl, hA);
  relu_ln_kernel<<<(N_NODES * 64 + 255) / 256, 256, 0, stream>>>(hA, g1, bt1);
  // layer 2
  node_gemm_kernel<64><<<(N_NODES + 63) / 64, 64, 0, stream>>>(hA, W2, b2, xl);
  hipMemsetAsync(out, 0, (size_t)N_NODES * 64 * 4, stream);
  edge_layer_kernel<<<N_EDGES / 64, 64, 0, stream>>>(attr, rowI, colI, nrm, Wc + 8192, bc + 128, xl, out);
}

// Round 2
// 1045.028 us; speedup vs baseline: 1.0781x; 1.0781x over previous
//
#include <hip/hip_runtime.h>

#define N_NODES 50000
#define N_EDGES 800000
#define LN_EPS 1e-5f
#define NBLK 196  // ceil(N_NODES/256)

static __device__ inline unsigned short f2bf(float f) {
  unsigned u = __float_as_uint(f);
  unsigned r = ((u >> 16) & 1) + 0x7fffu;
  return (unsigned short)((u + r) >> 16);
}

// ---- combine global edge transform with per-layer edge weight ----
__global__ void wcomb_kernel(const float* __restrict__ We, const float* __restrict__ be,
                             const float* __restrict__ eW, const float* __restrict__ eb,
                             float* __restrict__ Wc, float* __restrict__ bc) {
  int tid = threadIdx.x;
  for (int idx = tid; idx < 64 * 64; idx += 256) {
    int k = idx >> 6, c = idx & 63;
    float s = 0.f;
    for (int j = 0; j < 64; ++j) s = fmaf(We[k * 64 + j], eW[j * 64 + c], s);
    Wc[idx] = s;
  }
  if (tid < 64) {
    float s = eb[tid];
    for (int j = 0; j < 64; ++j) s = fmaf(be[j], eW[j * 64 + tid], s);
    bc[tid] = s;
  }
}

// ---- CSR build ----
__global__ void hist_kernel(const int* __restrict__ col, int* __restrict__ deg) {
  int e = blockIdx.x * blockDim.x + threadIdx.x;
  if (e < N_EDGES) atomicAdd(&deg[col[e]], 1);
}

__global__ __launch_bounds__(256) void scan1_kernel(const int* __restrict__ deg,
                                                    int* __restrict__ off, int* __restrict__ bsum) {
  __shared__ int s[256];
  int tid = threadIdx.x, i = blockIdx.x * 256 + tid;
  int v = (i < N_NODES) ? deg[i] : 0;
  s[tid] = v;
  __syncthreads();
  for (int d = 1; d < 256; d <<= 1) {
    int t = (tid >= d) ? s[tid - d] : 0;
    __syncthreads();
    s[tid] += t;
    __syncthreads();
  }
  if (i < N_NODES) off[i] = s[tid] - v;
  if (tid == 255) bsum[blockIdx.x] = s[255];
}

__global__ __launch_bounds__(256) void scan2_kernel(int* __restrict__ bsum) {
  __shared__ int s[256];
  int tid = threadIdx.x;
  int v = (tid < NBLK) ? bsum[tid] : 0;
  s[tid] = v;
  __syncthreads();
  for (int d = 1; d < 256; d <<= 1) {
    int t = (tid >= d) ? s[tid - d] : 0;
    __syncthreads();
    s[tid] += t;
    __syncthreads();
  }
  if (tid < NBLK) bsum[tid] = s[tid] - v;
}

__global__ void scan3_kernel(int* __restrict__ off, const int* __restrict__ bsum,
                             int* __restrict__ cursor) {
  int i = blockIdx.x * 256 + threadIdx.x;
  if (i < N_NODES) { int o = off[i] + bsum[blockIdx.x]; off[i] = o; cursor[i] = o; }
}

__global__ void dis_kernel(const int* __restrict__ deg, float* __restrict__ dis) {
  int n = blockIdx.x * blockDim.x + threadIdx.x;
  if (n < N_NODES) { int d = deg[n]; dis[n] = d > 0 ? rsqrtf((float)d) : 0.f; }
}

__global__ void scatter_kernel(const int* __restrict__ col, int* __restrict__ cursor,
                               int* __restrict__ perm) {
  int e = blockIdx.x * blockDim.x + threadIdx.x;
  if (e < N_EDGES) { int p = atomicAdd(&cursor[col[e]], 1); perm[p] = e; }
}

__global__ void meta_kernel(const int* __restrict__ perm, const int* __restrict__ row,
                            const int* __restrict__ col, const float* __restrict__ dis,
                            int* __restrict__ rowP, int* __restrict__ colP,
                            float* __restrict__ nrmP) {
  int i = blockIdx.x * blockDim.x + threadIdx.x;
  if (i < N_EDGES) {
    int e = perm[i];
    int r = row[e], c = col[e];
    rowP[i] = r; colP[i] = c; nrmP[i] = dis[r] * dis[c];
  }
}

__global__ void permA_kernel(const float* __restrict__ attr, const int* __restrict__ perm,
                             unsigned short* __restrict__ attrP) {
  int t = blockIdx.x * 256 + threadIdx.x;  // E*16 threads, 4 channels each
  int i = t >> 4, q = t & 15;
  if (i >= N_EDGES) return;
  int e = perm[i];
  float4 v = *(const float4*)(attr + (size_t)e * 64 + q * 4);
  ushort4 o = {f2bf(v.x), f2bf(v.y), f2bf(v.z), f2bf(v.w)};
  *(ushort4*)(attrP + (size_t)i * 64 + q * 4) = o;
}

// ---- node GEMM: Y[N,64] = X[N,K] @ W[K,64] + B ----
template <int K>
__global__ __launch_bounds__(64) void node_gemm_kernel(
    const float* __restrict__ X, const float* __restrict__ W, const float* __restrict__ B,
    float* __restrict__ Y) {
  int lane = threadIdx.x;
  int row = blockIdx.x * 64 + lane;
  int r = row < N_NODES ? row : N_NODES - 1;
  const float* xr = X + (long)r * K;
  float acc[64];
#pragma unroll
  for (int c = 0; c < 64; ++c) acc[c] = B[c];
#pragma unroll 1
  for (int kb = 0; kb < K; kb += 8) {
    float4 a0 = *(const float4*)(xr + kb);
    float4 a1 = *(const float4*)(xr + kb + 4);
    float av[8] = {a0.x, a0.y, a0.z, a0.w, a1.x, a1.y, a1.z, a1.w};
#pragma unroll
    for (int kk = 0; kk < 8; ++kk) {
      const float* wr = W + (kb + kk) * 64;
#pragma unroll
      for (int c = 0; c < 64; ++c) acc[c] = fmaf(av[kk], wr[c], acc[c]);
    }
  }
  if (row < N_NODES) {
    float* yr = Y + (long)row * 64;
#pragma unroll
    for (int c = 0; c < 64; c += 4) {
      float4 v = {acc[c], acc[c + 1], acc[c + 2], acc[c + 3]};
      *(float4*)(yr + c) = v;
    }
  }
}

// ---- fused edge kernel over CSR-sorted edges, segmented atomic scatter ----
template <bool BF16P>
__global__ __launch_bounds__(64) void edge_layer_kernel(
    const unsigned short* __restrict__ attrP, const float* __restrict__ attrF,
    const int* __restrict__ perm, const int* __restrict__ rowP, const int* __restrict__ colP,
    const float* __restrict__ nrmP, const float* __restrict__ Wc, const float* __restrict__ bc,
    const float* __restrict__ XL, float* __restrict__ OUT) {
  __shared__ float tile[64][65];  // [edge][channel]
  const int lane = threadIdx.x;
  const long e0 = (long)blockIdx.x * 64;

  if constexpr (!BF16P) {
#pragma unroll 8
    for (int i = 0; i < 64; ++i) {
      int e = perm[e0 + i];  // wave-uniform s_load
      tile[i][lane] = attrF[(size_t)e * 64 + lane];
    }
  }
  __syncthreads();

  float acc[64];
#pragma unroll
  for (int c = 0; c < 64; ++c) acc[c] = bc[c];

  const unsigned short* arow = attrP + (size_t)(e0 + lane) * 64;
#pragma unroll 1
  for (int kb = 0; kb < 64; kb += 8) {
    float av[8];
    if constexpr (BF16P) {
      uint4 w = *(const uint4*)(arow + kb);
      av[0] = __uint_as_float(w.x << 16); av[1] = __uint_as_float(w.x & 0xffff0000u);
      av[2] = __uint_as_float(w.y << 16); av[3] = __uint_as_float(w.y & 0xffff0000u);
      av[4] = __uint_as_float(w.z << 16); av[5] = __uint_as_float(w.z & 0xffff0000u);
      av[6] = __uint_as_float(w.w << 16); av[7] = __uint_as_float(w.w & 0xffff0000u);
    } else {
#pragma unroll
      for (int kk = 0; kk < 8; ++kk) av[kk] = tile[lane][kb + kk];
    }
#pragma unroll
    for (int kk = 0; kk < 8; ++kk) {
      const float* wr = Wc + (kb + kk) * 64;  // uniform -> s_load
#pragma unroll
      for (int c = 0; c < 64; ++c) acc[c] = fmaf(av[kk], wr[c], acc[c]);
    }
  }
  __syncthreads();
#pragma unroll
  for (int c = 0; c < 64; ++c) tile[lane][c] = acc[c];
  __syncthreads();

  // phase 2: lane = channel; edges sorted by col -> segmented accumulation
  int ccur = colP[e0];
  float accv = 0.f;
#pragma unroll 8
  for (int i = 0; i < 64; ++i) {
    int c = colP[e0 + i];        // uniform
    float nm = nrmP[e0 + i];     // uniform
    int r = rowP[e0 + i];        // uniform
    float v = nm * tile[i][lane] * XL[(size_t)r * 64 + lane];
    if (c != ccur) {             // wave-uniform branch
      atomicAdd(&OUT[(size_t)ccur * 64 + lane], accv);
      accv = v; ccur = c;
    } else {
      accv += v;
    }
  }
  atomicAdd(&OUT[(size_t)ccur * 64 + lane], accv);
}

// ---- fused ReLU + LayerNorm; one wave per row ----
__global__ void relu_ln_kernel(float* __restrict__ H, const float* __restrict__ G,
                               const float* __restrict__ B) {
  int t = blockIdx.x * blockDim.x + threadIdx.x;
  int row = t >> 6, lane = t & 63;
  if (row >= N_NODES) return;
  float v = H[(long)row * 64 + lane];
  v = fmaxf(v, 0.f);
  float s = v;
#pragma unroll
  for (int off = 32; off > 0; off >>= 1) s += __shfl_xor(s, off);
  float mu = s * (1.f / 64.f);
  float d = v - mu;
  float q = d * d;
#pragma unroll
  for (int off = 32; off > 0; off >>= 1) q += __shfl_xor(q, off);
  float var = q * (1.f / 64.f);
  H[(long)row * 64 + lane] = d * rsqrtf(var + LN_EPS) * G[lane] + B[lane];
}

extern "C" void kernel_launch(void* const* d_in, const int* in_sizes, int n_in,
                              void* d_out, int out_size, void* d_ws, size_t ws_size,
                              hipStream_t stream) {
  const float* x    = (const float*)d_in[0];
  const int* eidx   = (const int*)d_in[1];
  const float* attr = (const float*)d_in[2];
  const float* We  = (const float*)d_in[3];
  const float* be  = (const float*)d_in[4];
  const float* W0  = (const float*)d_in[5];  const float* b0  = (const float*)d_in[6];
  const float* eW0 = (const float*)d_in[7];  const float* eb0 = (const float*)d_in[8];
  const float* W1  = (const float*)d_in[9];  const float* b1  = (const float*)d_in[10];
  const float* eW1 = (const float*)d_in[11]; const float* eb1 = (const float*)d_in[12];
  const float* W2  = (const float*)d_in[13]; const float* b2  = (const float*)d_in[14];
  const float* eW2 = (const float*)d_in[15]; const float* eb2 = (const float*)d_in[16];
  const float* g0  = (const float*)d_in[17]; const float* bt0 = (const float*)d_in[18];
  const float* g1  = (const float*)d_in[19]; const float* bt1 = (const float*)d_in[20];
  const int* rowI = eidx;
  const int* colI = eidx + N_EDGES;

  char* base = (char*)d_ws;
  size_t pos = 0;
  auto alloc = [&](size_t b) -> char* {
    char* p = base + pos;
    pos += (b + 255) & ~(size_t)255;
    return p;
  };
  float* xl   = (float*)alloc((size_t)N_NODES * 64 * 4);
  float* nrmP = (float*)alloc((size_t)N_EDGES * 4);
  int* rowP   = (int*)alloc((size_t)N_EDGES * 4);
  int* colP   = (int*)alloc((size_t)N_EDGES * 4);
  int* perm   = (int*)alloc((size_t)N_EDGES * 4);
  int* degI   = (int*)alloc((size_t)N_NODES * 4);
  float* disF = (float*)alloc((size_t)N_NODES * 4);
  int* offB   = (int*)alloc((size_t)N_NODES * 4);
  int* curB   = (int*)alloc((size_t)N_NODES * 4);
  int* bsum   = (int*)alloc(256 * 4);
  float* Wc   = (float*)alloc(3 * 4096 * 4);
  float* bcC  = (float*)alloc(3 * 64 * 4);
  unsigned short* attrP = (unsigned short*)(base + pos);
  const bool bigws = (pos + (size_t)N_EDGES * 64 * 2) <= ws_size;
  float* hA = (float*)d_out;  // reuse output buffer as aggregation target

  // CSR build (by destination col)
  hipMemsetAsync(degI, 0, (size_t)N_NODES * 4, stream);
  hist_kernel<<<N_EDGES / 256, 256, 0, stream>>>(colI, degI);
  scan1_kernel<<<NBLK, 256, 0, stream>>>(degI, offB, bsum);
  scan2_kernel<<<1, 256, 0, stream>>>(bsum);
  scan3_kernel<<<NBLK, 256, 0, stream>>>(offB, bsum, curB);
  dis_kernel<<<NBLK, 256, 0, stream>>>(degI, disF);
  scatter_kernel<<<N_EDGES / 256, 256, 0, stream>>>(colI, curB, perm);
  meta_kernel<<<N_EDGES / 256, 256, 0, stream>>>(perm, rowI, colI, disF, rowP, colP, nrmP);
  if (bigws) permA_kernel<<<(N_EDGES * 16) / 256, 256, 0, stream>>>(attr, perm, attrP);

  wcomb_kernel<<<1, 256, 0, stream>>>(We, be, eW0, eb0, Wc,        bcC);
  wcomb_kernel<<<1, 256, 0, stream>>>(We, be, eW1, eb1, Wc + 4096, bcC + 64);
  wcomb_kernel<<<1, 256, 0, stream>>>(We, be, eW2, eb2, Wc + 8192, bcC + 128);

  for (int layer = 0; layer < 3; ++layer) {
    // node transform into xl
    if (layer == 0)
      node_gemm_kernel<128><<<(N_NODES + 63) / 64, 64, 0, stream>>>(x, W0, b0, xl);
    else if (layer == 1)
      node_gemm_kernel<64><<<(N_NODES + 63) / 64, 64, 0, stream>>>(hA, W1, b1, xl);
    else
      node_gemm_kernel<64><<<(N_NODES + 63) / 64, 64, 0, stream>>>(hA, W2, b2, xl);

    hipMemsetAsync(hA, 0, (size_t)N_NODES * 64 * 4, stream);
    const float* WcL = Wc + layer * 4096;
    const float* bcL = bcC + layer * 64;
    if (bigws)
      edge_layer_kernel<true><<<N_EDGES / 64, 64, 0, stream>>>(attrP, attr, perm, rowP, colP,
                                                               nrmP, WcL, bcL, xl, hA);
    else
      edge_layer_kernel<false><<<N_EDGES / 64, 64, 0, stream>>>(attrP, attr, perm, rowP, colP,
                                                                nrmP, WcL, bcL, xl, hA);
    if (layer == 0)
      relu_ln_kernel<<<(N_NODES * 64) / 256, 256, 0, stream>>>(hA, g0, bt0);
    else if (layer == 1)
      relu_ln_kernel<<<(N_NODES * 64) / 256, 256, 0, stream>>>(hA, g1, bt1);
  }
}

// Round 3
// 907.664 us; speedup vs baseline: 1.2412x; 1.1513x over previous
//
#include <hip/hip_runtime.h>

#define N_NODES 50000
#define N_EDGES 800000
#define LN_EPS 1e-5f
#define NBLK 196  // ceil(N_NODES/256)

static __device__ inline unsigned short f2bf(float f) {
  unsigned u = __float_as_uint(f);
  unsigned r = ((u >> 16) & 1) + 0x7fffu;
  return (unsigned short)((u + r) >> 16);
}
static __device__ inline float bf2f(unsigned short u) {
  return __uint_as_float((unsigned)u << 16);
}

// ---- combine global edge transform with per-layer edge weight ----
__global__ void wcomb_kernel(const float* __restrict__ We, const float* __restrict__ be,
                             const float* __restrict__ eW, const float* __restrict__ eb,
                             float* __restrict__ Wc, float* __restrict__ bc) {
  int tid = threadIdx.x;
  for (int idx = tid; idx < 64 * 64; idx += 256) {
    int k = idx >> 6, c = idx & 63;
    float s = 0.f;
    for (int j = 0; j < 64; ++j) s = fmaf(We[k * 64 + j], eW[j * 64 + c], s);
    Wc[idx] = s;
  }
  if (tid < 64) {
    float s = eb[tid];
    for (int j = 0; j < 64; ++j) s = fmaf(be[j], eW[j * 64 + tid], s);
    bc[tid] = s;
  }
}

// ---- CSR build ----
__global__ void hist_kernel(const int* __restrict__ col, int* __restrict__ deg) {
  int e = blockIdx.x * blockDim.x + threadIdx.x;
  if (e < N_EDGES) atomicAdd(&deg[col[e]], 1);
}

__global__ __launch_bounds__(256) void scan1_kernel(const int* __restrict__ deg,
                                                    int* __restrict__ off, int* __restrict__ bsum) {
  __shared__ int s[256];
  int tid = threadIdx.x, i = blockIdx.x * 256 + tid;
  int v = (i < N_NODES) ? deg[i] : 0;
  s[tid] = v;
  __syncthreads();
  for (int d = 1; d < 256; d <<= 1) {
    int t = (tid >= d) ? s[tid - d] : 0;
    __syncthreads();
    s[tid] += t;
    __syncthreads();
  }
  if (i < N_NODES) off[i] = s[tid] - v;
  if (tid == 255) bsum[blockIdx.x] = s[255];
}

__global__ __launch_bounds__(256) void scan2_kernel(int* __restrict__ bsum) {
  __shared__ int s[256];
  int tid = threadIdx.x;
  int v = (tid < NBLK) ? bsum[tid] : 0;
  s[tid] = v;
  __syncthreads();
  for (int d = 1; d < 256; d <<= 1) {
    int t = (tid >= d) ? s[tid - d] : 0;
    __syncthreads();
    s[tid] += t;
    __syncthreads();
  }
  if (tid < NBLK) bsum[tid] = s[tid] - v;
}

__global__ void scan3_kernel(int* __restrict__ off, const int* __restrict__ bsum,
                             int* __restrict__ cursor) {
  int i = blockIdx.x * 256 + threadIdx.x;
  if (i < N_NODES) { int o = off[i] + bsum[blockIdx.x]; off[i] = o; cursor[i] = o; }
}

__global__ void dis_kernel(const int* __restrict__ deg, float* __restrict__ dis) {
  int n = blockIdx.x * blockDim.x + threadIdx.x;
  if (n < N_NODES) { int d = deg[n]; dis[n] = d > 0 ? rsqrtf((float)d) : 0.f; }
}

__global__ void scatter_kernel(const int* __restrict__ col, int* __restrict__ cursor,
                               int* __restrict__ perm) {
  int e = blockIdx.x * blockDim.x + threadIdx.x;
  if (e < N_EDGES) { int p = atomicAdd(&cursor[col[e]], 1); perm[p] = e; }
}

__global__ void meta_kernel(const int* __restrict__ perm, const int* __restrict__ row,
                            const int* __restrict__ col, const float* __restrict__ dis,
                            int* __restrict__ rowP, int* __restrict__ colP,
                            float* __restrict__ nrmP) {
  int i = blockIdx.x * blockDim.x + threadIdx.x;
  if (i < N_EDGES) {
    int e = perm[i];
    int r = row[e], c = col[e];
    rowP[i] = r; colP[i] = c; nrmP[i] = dis[r] * dis[c];
  }
}

__global__ void permA_kernel(const float* __restrict__ attr, const int* __restrict__ perm,
                             unsigned short* __restrict__ attrP) {
  int t = blockIdx.x * 256 + threadIdx.x;  // E*16 threads, 4 channels each
  int i = t >> 4, q = t & 15;
  if (i >= N_EDGES) return;
  int e = perm[i];
  float4 v = *(const float4*)(attr + (size_t)e * 64 + q * 4);
  ushort4 o = {f2bf(v.x), f2bf(v.y), f2bf(v.z), f2bf(v.w)};
  *(ushort4*)(attrP + (size_t)i * 64 + q * 4) = o;
}

// ---- node GEMM: Y[N,64] = X[N,K] @ W[K,64] + B ----
template <int K>
__global__ __launch_bounds__(64) void node_gemm_kernel(
    const float* __restrict__ X, const float* __restrict__ W, const float* __restrict__ B,
    float* __restrict__ Y) {
  int lane = threadIdx.x;
  int row = blockIdx.x * 64 + lane;
  int r = row < N_NODES ? row : N_NODES - 1;
  const float* xr = X + (long)r * K;
  float acc[64];
#pragma unroll
  for (int c = 0; c < 64; ++c) acc[c] = B[c];
#pragma unroll 2
  for (int kb = 0; kb < K; kb += 8) {
    float4 a0 = *(const float4*)(xr + kb);
    float4 a1 = *(const float4*)(xr + kb + 4);
    float av[8] = {a0.x, a0.y, a0.z, a0.w, a1.x, a1.y, a1.z, a1.w};
#pragma unroll
    for (int kk = 0; kk < 8; ++kk) {
      const float* wr = W + (kb + kk) * 64;
#pragma unroll
      for (int c = 0; c < 64; ++c) acc[c] = fmaf(av[kk], wr[c], acc[c]);
    }
  }
  if (row < N_NODES) {
    float* yr = Y + (long)row * 64;
#pragma unroll
    for (int c = 0; c < 64; c += 4) {
      float4 v = {acc[c], acc[c + 1], acc[c + 2], acc[c + 3]};
      *(float4*)(yr + c) = v;
    }
  }
}

// ---- fused edge kernel over CSR-sorted edges, segmented atomic scatter ----
__global__ __launch_bounds__(64, 4) void edge_layer_kernel(
    const unsigned short* __restrict__ attrP, const int* __restrict__ rowP,
    const int* __restrict__ colP, const float* __restrict__ nrmP,
    const float* __restrict__ Wc, const float* __restrict__ bc,
    const float* __restrict__ XL, float* __restrict__ OUT) {
  __shared__ unsigned short tile[64][66];  // bf16 [edge][channel]; stride 33 dwords (odd)
  const int lane = threadIdx.x;
  const long e0 = (long)blockIdx.x * 64;

  float acc[64];
#pragma unroll
  for (int c = 0; c < 64; ++c) acc[c] = bc[c];

  const unsigned short* arow = attrP + (size_t)(e0 + lane) * 64;
#pragma unroll 2
  for (int kb = 0; kb < 64; kb += 8) {
    uint4 w = *(const uint4*)(arow + kb);
    float av[8];
    av[0] = __uint_as_float(w.x << 16); av[1] = __uint_as_float(w.x & 0xffff0000u);
    av[2] = __uint_as_float(w.y << 16); av[3] = __uint_as_float(w.y & 0xffff0000u);
    av[4] = __uint_as_float(w.z << 16); av[5] = __uint_as_float(w.z & 0xffff0000u);
    av[6] = __uint_as_float(w.w << 16); av[7] = __uint_as_float(w.w & 0xffff0000u);
#pragma unroll
    for (int kk = 0; kk < 8; ++kk) {
      const float* wr = Wc + (kb + kk) * 64;  // wave-uniform -> s_load
#pragma unroll
      for (int c = 0; c < 64; ++c) acc[c] = fmaf(av[kk], wr[c], acc[c]);
    }
  }
  // acc -> bf16 tile (transposed access in phase 2)
#pragma unroll
  for (int c = 0; c < 64; c += 2) {
    unsigned short lo = f2bf(acc[c]), hi = f2bf(acc[c + 1]);
    *(unsigned int*)&tile[lane][c] = (unsigned)lo | ((unsigned)hi << 16);
  }
  __syncthreads();

  // phase 2: lane = channel; edges sorted by col -> segmented accumulation.
  // Gathers decoupled from the branchy flush loop; 16 in flight + prefetch.
  float xv[16], xn[16];
#pragma unroll
  for (int j = 0; j < 16; ++j) {
    int r = rowP[e0 + j];  // wave-uniform
    xv[j] = XL[(size_t)r * 64 + lane];
  }
  int ccur = colP[e0];
  float accv = 0.f;
#pragma unroll
  for (int ib = 0; ib < 64; ib += 16) {
    if (ib + 16 < 64) {
#pragma unroll
      for (int j = 0; j < 16; ++j) {
        int r = rowP[e0 + ib + 16 + j];
        xn[j] = XL[(size_t)r * 64 + lane];
      }
    }
#pragma unroll
    for (int j = 0; j < 16; ++j) {
      int i = ib + j;
      int c = colP[e0 + i];     // uniform
      float nm = nrmP[e0 + i];  // uniform
      float v = nm * bf2f(tile[i][lane]) * xv[j];
      if (c != ccur) {          // wave-uniform branch
        atomicAdd(&OUT[(size_t)ccur * 64 + lane], accv);
        accv = v; ccur = c;
      } else {
        accv += v;
      }
    }
#pragma unroll
    for (int j = 0; j < 16; ++j) xv[j] = xn[j];
  }
  atomicAdd(&OUT[(size_t)ccur * 64 + lane], accv);
}

// ---- fused ReLU + LayerNorm; one wave per row ----
__global__ void relu_ln_kernel(float* __restrict__ H, const float* __restrict__ G,
                               const float* __restrict__ B) {
  int t = blockIdx.x * blockDim.x + threadIdx.x;
  int row = t >> 6, lane = t & 63;
  if (row >= N_NODES) return;
  float v = H[(long)row * 64 + lane];
  v = fmaxf(v, 0.f);
  float s = v;
#pragma unroll
  for (int off = 32; off > 0; off >>= 1) s += __shfl_xor(s, off);
  float mu = s * (1.f / 64.f);
  float d = v - mu;
  float q = d * d;
#pragma unroll
  for (int off = 32; off > 0; off >>= 1) q += __shfl_xor(q, off);
  float var = q * (1.f / 64.f);
  H[(long)row * 64 + lane] = d * rsqrtf(var + LN_EPS) * G[lane] + B[lane];
}

extern "C" void kernel_launch(void* const* d_in, const int* in_sizes, int n_in,
                              void* d_out, int out_size, void* d_ws, size_t ws_size,
                              hipStream_t stream) {
  const float* x    = (const float*)d_in[0];
  const int* eidx   = (const int*)d_in[1];
  const float* attr = (const float*)d_in[2];
  const float* We  = (const float*)d_in[3];
  const float* be  = (const float*)d_in[4];
  const float* W0  = (const float*)d_in[5];  const float* b0  = (const float*)d_in[6];
  const float* eW0 = (const float*)d_in[7];  const float* eb0 = (const float*)d_in[8];
  const float* W1  = (const float*)d_in[9];  const float* b1  = (const float*)d_in[10];
  const float* eW1 = (const float*)d_in[11]; const float* eb1 = (const float*)d_in[12];
  const float* W2  = (const float*)d_in[13]; const float* b2  = (const float*)d_in[14];
  const float* eW2 = (const float*)d_in[15]; const float* eb2 = (const float*)d_in[16];
  const float* g0  = (const float*)d_in[17]; const float* bt0 = (const float*)d_in[18];
  const float* g1  = (const float*)d_in[19]; const float* bt1 = (const float*)d_in[20];
  const int* rowI = eidx;
  const int* colI = eidx + N_EDGES;

  char* base = (char*)d_ws;
  size_t pos = 0;
  auto alloc = [&](size_t b) -> char* {
    char* p = base + pos;
    pos += (b + 255) & ~(size_t)255;
    return p;
  };
  float* xl   = (float*)alloc((size_t)N_NODES * 64 * 4);
  float* nrmP = (float*)alloc((size_t)N_EDGES * 4);
  int* rowP   = (int*)alloc((size_t)N_EDGES * 4);
  int* colP   = (int*)alloc((size_t)N_EDGES * 4);
  int* perm   = (int*)alloc((size_t)N_EDGES * 4);
  int* degI   = (int*)alloc((size_t)N_NODES * 4);
  float* disF = (float*)alloc((size_t)N_NODES * 4);
  int* offB   = (int*)alloc((size_t)N_NODES * 4);
  int* curB   = (int*)alloc((size_t)N_NODES * 4);
  int* bsum   = (int*)alloc(256 * 4);
  float* Wc   = (float*)alloc(3 * 4096 * 4);
  float* bcC  = (float*)alloc(3 * 64 * 4);
  unsigned short* attrP = (unsigned short*)alloc((size_t)N_EDGES * 64 * 2);
  (void)ws_size;
  float* hA = (float*)d_out;  // reuse output buffer as aggregation target

  // CSR build (by destination col)
  hipMemsetAsync(degI, 0, (size_t)N_NODES * 4, stream);
  hist_kernel<<<N_EDGES / 256, 256, 0, stream>>>(colI, degI);
  scan1_kernel<<<NBLK, 256, 0, stream>>>(degI, offB, bsum);
  scan2_kernel<<<1, 256, 0, stream>>>(bsum);
  scan3_kernel<<<NBLK, 256, 0, stream>>>(offB, bsum, curB);
  dis_kernel<<<NBLK, 256, 0, stream>>>(degI, disF);
  scatter_kernel<<<N_EDGES / 256, 256, 0, stream>>>(colI, curB, perm);
  meta_kernel<<<N_EDGES / 256, 256, 0, stream>>>(perm, rowI, colI, disF, rowP, colP, nrmP);
  permA_kernel<<<(N_EDGES * 16) / 256, 256, 0, stream>>>(attr, perm, attrP);

  wcomb_kernel<<<1, 256, 0, stream>>>(We, be, eW0, eb0, Wc,        bcC);
  wcomb_kernel<<<1, 256, 0, stream>>>(We, be, eW1, eb1, Wc + 4096, bcC + 64);
  wcomb_kernel<<<1, 256, 0, stream>>>(We, be, eW2, eb2, Wc + 8192, bcC + 128);

  for (int layer = 0; layer < 3; ++layer) {
    if (layer == 0)
      node_gemm_kernel<128><<<(N_NODES + 63) / 64, 64, 0, stream>>>(x, W0, b0, xl);
    else if (layer == 1)
      node_gemm_kernel<64><<<(N_NODES + 63) / 64, 64, 0, stream>>>(hA, W1, b1, xl);
    else
      node_gemm_kernel<64><<<(N_NODES + 63) / 64, 64, 0, stream>>>(hA, W2, b2, xl);

    hipMemsetAsync(hA, 0, (size_t)N_NODES * 64 * 4, stream);
    const float* WcL = Wc + layer * 4096;
    const float* bcL = bcC + layer * 64;
    edge_layer_kernel<<<N_EDGES / 64, 64, 0, stream>>>(attrP, rowP, colP, nrmP, WcL, bcL, xl, hA);
    if (layer == 0)
      relu_ln_kernel<<<(N_NODES * 64) / 256, 256, 0, stream>>>(hA, g0, bt0);
    else if (layer == 1)
      relu_ln_kernel<<<(N_NODES * 64) / 256, 256, 0, stream>>>(hA, g1, bt1);
  }
}

// Round 4
// 595.238 us; speedup vs baseline: 1.8927x; 1.5249x over previous
//
#include <hip/hip_runtime.h>

#define N_NODES 50000
#define N_EDGES 800000
#define LN_EPS 1e-5f
#define NBLK 196  // ceil(N_NODES/256)

typedef __attribute__((ext_vector_type(8))) short bf16x8;
typedef __attribute__((ext_vector_type(4))) float f32x4;

static __device__ inline unsigned short f2bf(float f) {
  unsigned u = __float_as_uint(f);
  unsigned r = ((u >> 16) & 1) + 0x7fffu;
  return (unsigned short)((u + r) >> 16);
}
static __device__ inline float bf2f(unsigned short u) {
  return __uint_as_float((unsigned)u << 16);
}

// ---- combined edge transforms for all 3 layers: WcT[L][n][k] bf16, bcC[L][n] ----
__global__ void wcomb_kernel(const float* __restrict__ We, const float* __restrict__ be,
                             const float* __restrict__ eW0, const float* __restrict__ eb0,
                             const float* __restrict__ eW1, const float* __restrict__ eb1,
                             const float* __restrict__ eW2, const float* __restrict__ eb2,
                             unsigned short* __restrict__ WcT, float* __restrict__ bcC) {
  int L = blockIdx.x;
  const float* eW = L == 0 ? eW0 : (L == 1 ? eW1 : eW2);
  const float* eb = L == 0 ? eb0 : (L == 1 ? eb1 : eb2);
  int tid = threadIdx.x;
  for (int idx = tid; idx < 64 * 64; idx += 256) {
    int k = idx >> 6, c = idx & 63;
    float s = 0.f;
    for (int j = 0; j < 64; ++j) s = fmaf(We[k * 64 + j], eW[j * 64 + c], s);
    WcT[L * 4096 + c * 64 + k] = f2bf(s);  // transposed: [n][k]
  }
  if (tid < 64) {
    float s = eb[tid];
    for (int j = 0; j < 64; ++j) s = fmaf(be[j], eW[j * 64 + tid], s);
    bcC[L * 64 + tid] = s;
  }
}

// ---- CSR build ----
__global__ void hist_kernel(const int* __restrict__ col, int* __restrict__ deg) {
  int e = blockIdx.x * blockDim.x + threadIdx.x;
  if (e < N_EDGES) atomicAdd(&deg[col[e]], 1);
}

__global__ __launch_bounds__(256) void scan1_kernel(const int* __restrict__ deg,
                                                    int* __restrict__ off, int* __restrict__ bsum) {
  __shared__ int s[256];
  int tid = threadIdx.x, i = blockIdx.x * 256 + tid;
  int v = (i < N_NODES) ? deg[i] : 0;
  s[tid] = v;
  __syncthreads();
  for (int d = 1; d < 256; d <<= 1) {
    int t = (tid >= d) ? s[tid - d] : 0;
    __syncthreads();
    s[tid] += t;
    __syncthreads();
  }
  if (i < N_NODES) off[i] = s[tid] - v;
  if (tid == 255) bsum[blockIdx.x] = s[255];
}

__global__ __launch_bounds__(256) void scan2_kernel(int* __restrict__ bsum) {
  __shared__ int s[256];
  int tid = threadIdx.x;
  int v = (tid < NBLK) ? bsum[tid] : 0;
  s[tid] = v;
  __syncthreads();
  for (int d = 1; d < 256; d <<= 1) {
    int t = (tid >= d) ? s[tid - d] : 0;
    __syncthreads();
    s[tid] += t;
    __syncthreads();
  }
  if (tid < NBLK) bsum[tid] = s[tid] - v;
}

__global__ void scan3_kernel(int* __restrict__ off, const int* __restrict__ bsum,
                             int* __restrict__ cursor) {
  int i = blockIdx.x * 256 + threadIdx.x;
  if (i < N_NODES) { int o = off[i] + bsum[blockIdx.x]; off[i] = o; cursor[i] = o; }
}

__global__ void dis_kernel(const int* __restrict__ deg, float* __restrict__ dis) {
  int n = blockIdx.x * blockDim.x + threadIdx.x;
  if (n < N_NODES) { int d = deg[n]; dis[n] = d > 0 ? rsqrtf((float)d) : 0.f; }
}

__global__ void scatter_kernel(const int* __restrict__ col, int* __restrict__ cursor,
                               int* __restrict__ perm) {
  int e = blockIdx.x * blockDim.x + threadIdx.x;
  if (e < N_EDGES) { int p = atomicAdd(&cursor[col[e]], 1); perm[p] = e; }
}

__global__ void meta_kernel(const int* __restrict__ perm, const int* __restrict__ row,
                            const int* __restrict__ col, const float* __restrict__ dis,
                            int* __restrict__ rowP, int* __restrict__ colP,
                            float* __restrict__ nrmP) {
  int i = blockIdx.x * blockDim.x + threadIdx.x;
  if (i < N_EDGES) {
    int e = perm[i];
    int r = row[e], c = col[e];
    rowP[i] = r; colP[i] = c; nrmP[i] = dis[r] * dis[c];
  }
}

__global__ void permA_kernel(const float* __restrict__ attr, const int* __restrict__ perm,
                             unsigned short* __restrict__ attrP) {
  int t = blockIdx.x * 256 + threadIdx.x;  // E*16 threads, 4 channels each
  int i = t >> 4, q = t & 15;
  if (i >= N_EDGES) return;
  int e = perm[i];
  float4 v = *(const float4*)(attr + (size_t)e * 64 + q * 4);
  ushort4 o = {f2bf(v.x), f2bf(v.y), f2bf(v.z), f2bf(v.w)};
  *(ushort4*)(attrP + (size_t)i * 64 + q * 4) = o;
}

// ---- node GEMM K=128 (layer 0), streaming, bf16 out ----
__global__ __launch_bounds__(256, 4) void node_gemm128_kernel(
    const float* __restrict__ X, const float* __restrict__ W, const float* __restrict__ B,
    unsigned short* __restrict__ Y) {
  int row = blockIdx.x * 256 + threadIdx.x;
  int r = row < N_NODES ? row : N_NODES - 1;
  const float* xr = X + (long)r * 128;
  float acc[64];
#pragma unroll
  for (int c = 0; c < 64; ++c) acc[c] = B[c];
#pragma unroll 2
  for (int kb = 0; kb < 128; kb += 8) {
    float4 a0 = *(const float4*)(xr + kb);
    float4 a1 = *(const float4*)(xr + kb + 4);
    float av[8] = {a0.x, a0.y, a0.z, a0.w, a1.x, a1.y, a1.z, a1.w};
#pragma unroll
    for (int kk = 0; kk < 8; ++kk) {
      const float* wr = W + (kb + kk) * 64;
#pragma unroll
      for (int c = 0; c < 64; ++c) acc[c] = fmaf(av[kk], wr[c], acc[c]);
    }
  }
  if (row < N_NODES) {
    unsigned* yo = (unsigned*)(Y + (size_t)row * 64);
#pragma unroll
    for (int c = 0; c < 64; c += 2)
      yo[c >> 1] = (unsigned)f2bf(acc[c]) | ((unsigned)f2bf(acc[c + 1]) << 16);
  }
}

// ---- node GEMM K=64 with fused input ReLU+LayerNorm, bf16 out ----
__global__ __launch_bounds__(256, 3) void node_gemm64_kernel(
    const float* __restrict__ X, const float* __restrict__ W, const float* __restrict__ B,
    const float* __restrict__ G, const float* __restrict__ BT,
    unsigned short* __restrict__ Y) {
  int row = blockIdx.x * 256 + threadIdx.x;
  int r = row < N_NODES ? row : N_NODES - 1;
  const float* xr = X + (long)r * 64;
  float xv[64];
#pragma unroll
  for (int k = 0; k < 64; k += 4) {
    float4 v = *(const float4*)(xr + k);
    xv[k] = v.x; xv[k + 1] = v.y; xv[k + 2] = v.z; xv[k + 3] = v.w;
  }
  // ReLU + LN (row fully in registers)
  float mu = 0.f;
#pragma unroll
  for (int k = 0; k < 64; ++k) { xv[k] = fmaxf(xv[k], 0.f); mu += xv[k]; }
  mu *= (1.f / 64.f);
  float var = 0.f;
#pragma unroll
  for (int k = 0; k < 64; ++k) { float d = xv[k] - mu; var += d * d; }
  float is = rsqrtf(var * (1.f / 64.f) + LN_EPS);
#pragma unroll
  for (int k = 0; k < 64; ++k) xv[k] = (xv[k] - mu) * is * G[k] + BT[k];

  float acc[64];
#pragma unroll
  for (int c = 0; c < 64; ++c) acc[c] = B[c];
#pragma unroll 2
  for (int k = 0; k < 64; ++k) {
    const float* wr = W + k * 64;
#pragma unroll
    for (int c = 0; c < 64; ++c) acc[c] = fmaf(xv[k], wr[c], acc[c]);
  }
  if (row < N_NODES) {
    unsigned* yo = (unsigned*)(Y + (size_t)row * 64);
#pragma unroll
    for (int c = 0; c < 64; c += 2)
      yo[c >> 1] = (unsigned)f2bf(acc[c]) | ((unsigned)f2bf(acc[c + 1]) << 16);
  }
}

// ---- fused edge kernel: MFMA edge-GEMM + LDS transpose + segmented gather/scatter ----
// 256 threads = 4 waves, 256 edges/block; each wave owns 64 edges end-to-end.
__global__ __launch_bounds__(256, 3) void edge_layer_kernel(
    const unsigned short* __restrict__ attrP, const int* __restrict__ rowP,
    const int* __restrict__ colP, const float* __restrict__ nrmP,
    const unsigned short* __restrict__ WcT,  // bf16 [64 n][64 k]
    const float* __restrict__ bc,
    const unsigned short* __restrict__ XLb,  // bf16 [N][64]
    float* __restrict__ OUT) {
  __shared__ unsigned short tile[256][66];  // bf16 efl*nrm, [edge][channel]
  __shared__ float nrm_s[256];
  const int tid = threadIdx.x;
  const int wid = tid >> 6, lane = tid & 63;
  const int e0 = blockIdx.x * 256;
  const int wb = wid * 64;
  const int lr = lane & 15, lg = lane >> 4;

  nrm_s[tid] = nrmP[e0 + tid];

  // B fragments (WcT rows are contiguous in k) + bias
  bf16x8 bfrag[4][2];
  float bias[4];
#pragma unroll
  for (int tn = 0; tn < 4; ++tn) {
    bias[tn] = bc[tn * 16 + lr];
#pragma unroll
    for (int kb = 0; kb < 2; ++kb)
      bfrag[tn][kb] = *(const bf16x8*)(WcT + (tn * 16 + lr) * 64 + kb * 32 + lg * 8);
  }
  // A fragments (attrP rows contiguous in k)
  bf16x8 afrag[4][2];
#pragma unroll
  for (int tm = 0; tm < 4; ++tm)
#pragma unroll
    for (int kb = 0; kb < 2; ++kb)
      afrag[tm][kb] = *(const bf16x8*)(attrP + (size_t)(e0 + wb + tm * 16 + lr) * 64 + kb * 32 + lg * 8);

  f32x4 acc[4][4];
#pragma unroll
  for (int tm = 0; tm < 4; ++tm)
#pragma unroll
    for (int tn = 0; tn < 4; ++tn) {
      f32x4 c = {bias[tn], bias[tn], bias[tn], bias[tn]};
      c = __builtin_amdgcn_mfma_f32_16x16x32_bf16(afrag[tm][0], bfrag[tn][0], c, 0, 0, 0);
      c = __builtin_amdgcn_mfma_f32_16x16x32_bf16(afrag[tm][1], bfrag[tn][1], c, 0, 0, 0);
      acc[tm][tn] = c;
    }

  // epilogue: D(row=(lane>>4)*4+j, col=lane&15) -> tile[edge][channel], scaled by nrm
#pragma unroll
  for (int tm = 0; tm < 4; ++tm)
#pragma unroll
    for (int tn = 0; tn < 4; ++tn)
#pragma unroll
      for (int j = 0; j < 4; ++j) {
        int el = wb + tm * 16 + lg * 4 + j;
        tile[el][tn * 16 + lr] = f2bf(acc[tm][tn][j] * nrm_s[el]);
      }
  __syncthreads();

  // phase 2: lane = channel; 16-deep gather pipeline; segmented atomic flush
  const int eb = __builtin_amdgcn_readfirstlane(e0 + wb);  // scalar base -> s_loads
  unsigned short xv[16], xn[16];
#pragma unroll
  for (int j = 0; j < 16; ++j)
    xv[j] = XLb[(size_t)rowP[eb + j] * 64 + lane];
  int ccur = colP[eb];
  float accv = 0.f;
#pragma unroll
  for (int ib = 0; ib < 64; ib += 16) {
    if (ib + 16 < 64) {
#pragma unroll
      for (int j = 0; j < 16; ++j)
        xn[j] = XLb[(size_t)rowP[eb + ib + 16 + j] * 64 + lane];
    }
#pragma unroll
    for (int j = 0; j < 16; ++j) {
      int i = ib + j;
      float v = bf2f(tile[wb + i][lane]) * bf2f(xv[j]);
      int c = colP[eb + i];  // scalar
      if (c != ccur) {       // wave-uniform branch
        atomicAdd(&OUT[(size_t)ccur * 64 + lane], accv);
        accv = v; ccur = c;
      } else {
        accv += v;
      }
    }
#pragma unroll
    for (int j = 0; j < 16; ++j) xv[j] = xn[j];
  }
  atomicAdd(&OUT[(size_t)ccur * 64 + lane], accv);
}

extern "C" void kernel_launch(void* const* d_in, const int* in_sizes, int n_in,
                              void* d_out, int out_size, void* d_ws, size_t ws_size,
                              hipStream_t stream) {
  const float* x    = (const float*)d_in[0];
  const int* eidx   = (const int*)d_in[1];
  const float* attr = (const float*)d_in[2];
  const float* We  = (const float*)d_in[3];
  const float* be  = (const float*)d_in[4];
  const float* W0  = (const float*)d_in[5];  const float* b0  = (const float*)d_in[6];
  const float* eW0 = (const float*)d_in[7];  const float* eb0 = (const float*)d_in[8];
  const float* W1  = (const float*)d_in[9];  const float* b1  = (const float*)d_in[10];
  const float* eW1 = (const float*)d_in[11]; const float* eb1 = (const float*)d_in[12];
  const float* W2  = (const float*)d_in[13]; const float* b2  = (const float*)d_in[14];
  const float* eW2 = (const float*)d_in[15]; const float* eb2 = (const float*)d_in[16];
  const float* g0  = (const float*)d_in[17]; const float* bt0 = (const float*)d_in[18];
  const float* g1  = (const float*)d_in[19]; const float* bt1 = (const float*)d_in[20];
  const int* rowI = eidx;
  const int* colI = eidx + N_EDGES;

  char* base = (char*)d_ws;
  size_t pos = 0;
  auto alloc = [&](size_t b) -> char* {
    char* p = base + pos;
    pos += (b + 255) & ~(size_t)255;
    return p;
  };
  unsigned short* XLb = (unsigned short*)alloc((size_t)N_NODES * 64 * 2);
  float* nrmP = (float*)alloc((size_t)N_EDGES * 4);
  int* rowP   = (int*)alloc((size_t)N_EDGES * 4);
  int* colP   = (int*)alloc((size_t)N_EDGES * 4);
  int* perm   = (int*)alloc((size_t)N_EDGES * 4);
  int* degI   = (int*)alloc((size_t)N_NODES * 4);
  float* disF = (float*)alloc((size_t)N_NODES * 4);
  int* offB   = (int*)alloc((size_t)N_NODES * 4);
  int* curB   = (int*)alloc((size_t)N_NODES * 4);
  int* bsum   = (int*)alloc(256 * 4);
  unsigned short* WcT = (unsigned short*)alloc(3 * 4096 * 2);
  float* bcC  = (float*)alloc(3 * 64 * 4);
  unsigned short* attrP = (unsigned short*)alloc((size_t)N_EDGES * 64 * 2);
  (void)ws_size;
  float* hA = (float*)d_out;  // aggregation buffer (final layer writes here anyway)

  // CSR build (sorted by destination col)
  hipMemsetAsync(degI, 0, (size_t)N_NODES * 4, stream);
  hist_kernel<<<N_EDGES / 256, 256, 0, stream>>>(colI, degI);
  scan1_kernel<<<NBLK, 256, 0, stream>>>(degI, offB, bsum);
  scan2_kernel<<<1, 256, 0, stream>>>(bsum);
  scan3_kernel<<<NBLK, 256, 0, stream>>>(offB, bsum, curB);
  dis_kernel<<<NBLK, 256, 0, stream>>>(degI, disF);
  scatter_kernel<<<N_EDGES / 256, 256, 0, stream>>>(colI, curB, perm);
  meta_kernel<<<N_EDGES / 256, 256, 0, stream>>>(perm, rowI, colI, disF, rowP, colP, nrmP);
  permA_kernel<<<(N_EDGES * 16) / 256, 256, 0, stream>>>(attr, perm, attrP);
  wcomb_kernel<<<3, 256, 0, stream>>>(We, be, eW0, eb0, eW1, eb1, eW2, eb2, WcT, bcC);

  // layer 0
  node_gemm128_kernel<<<NBLK, 256, 0, stream>>>(x, W0, b0, XLb);
  hipMemsetAsync(hA, 0, (size_t)N_NODES * 64 * 4, stream);
  edge_layer_kernel<<<N_EDGES / 256, 256, 0, stream>>>(attrP, rowP, colP, nrmP, WcT, bcC, XLb, hA);
  // layer 1 (input ReLU+LN fused into node GEMM)
  node_gemm64_kernel<<<NBLK, 256, 0, stream>>>(hA, W1, b1, g0, bt0, XLb);
  hipMemsetAsync(hA, 0, (size_t)N_NODES * 64 * 4, stream);
  edge_layer_kernel<<<N_EDGES / 256, 256, 0, stream>>>(attrP, rowP, colP, nrmP, WcT + 4096, bcC + 64, XLb, hA);
  // layer 2
  node_gemm64_kernel<<<NBLK, 256, 0, stream>>>(hA, W2, b2, g1, bt1, XLb);
  hipMemsetAsync(hA, 0, (size_t)N_NODES * 64 * 4, stream);
  edge_layer_kernel<<<N_EDGES / 256, 256, 0, stream>>>(attrP, rowP, colP, nrmP, WcT + 8192, bcC + 128, XLb, hA);
}

// Round 5
// 562.102 us; speedup vs baseline: 2.0043x; 1.0589x over previous
//
#include <hip/hip_runtime.h>

#define N_NODES 50000
#define N_EDGES 800000
#define LN_EPS 1e-5f
#define NBLK 196  // ceil(N_NODES/256)

typedef __attribute__((ext_vector_type(8))) short bf16x8;
typedef __attribute__((ext_vector_type(4))) float f32x4;

static __device__ inline unsigned short f2bf(float f) {
  unsigned u = __float_as_uint(f);
  unsigned r = ((u >> 16) & 1) + 0x7fffu;
  return (unsigned short)((u + r) >> 16);
}
static __device__ inline float bf2f(unsigned short u) {
  return __uint_as_float((unsigned)u << 16);
}

// ---- combined edge transforms for all 3 layers: WcT[L][n][k] bf16, bcC[L][n] ----
__global__ void wcomb_kernel(const float* __restrict__ We, const float* __restrict__ be,
                             const float* __restrict__ eW0, const float* __restrict__ eb0,
                             const float* __restrict__ eW1, const float* __restrict__ eb1,
                             const float* __restrict__ eW2, const float* __restrict__ eb2,
                             unsigned short* __restrict__ WcT, float* __restrict__ bcC) {
  int L = blockIdx.x;
  const float* eW = L == 0 ? eW0 : (L == 1 ? eW1 : eW2);
  const float* eb = L == 0 ? eb0 : (L == 1 ? eb1 : eb2);
  int tid = threadIdx.x;
  for (int idx = tid; idx < 64 * 64; idx += 256) {
    int k = idx >> 6, c = idx & 63;
    float s = 0.f;
    for (int j = 0; j < 64; ++j) s = fmaf(We[k * 64 + j], eW[j * 64 + c], s);
    WcT[L * 4096 + c * 64 + k] = f2bf(s);  // transposed: [n][k]
  }
  if (tid < 64) {
    float s = eb[tid];
    for (int j = 0; j < 64; ++j) s = fmaf(be[j], eW[j * 64 + tid], s);
    bcC[L * 64 + tid] = s;
  }
}

// ---- CSR build ----
__global__ void hist_kernel(const int* __restrict__ col, int* __restrict__ deg) {
  int e = blockIdx.x * blockDim.x + threadIdx.x;
  if (e < N_EDGES) atomicAdd(&deg[col[e]], 1);
}

__global__ __launch_bounds__(256) void scan1_kernel(const int* __restrict__ deg,
                                                    int* __restrict__ off, int* __restrict__ bsum) {
  __shared__ int s[256];
  int tid = threadIdx.x, i = blockIdx.x * 256 + tid;
  int v = (i < N_NODES) ? deg[i] : 0;
  s[tid] = v;
  __syncthreads();
  for (int d = 1; d < 256; d <<= 1) {
    int t = (tid >= d) ? s[tid - d] : 0;
    __syncthreads();
    s[tid] += t;
    __syncthreads();
  }
  if (i < N_NODES) off[i] = s[tid] - v;
  if (tid == 255) bsum[blockIdx.x] = s[255];
}

__global__ __launch_bounds__(256) void scan2_kernel(int* __restrict__ bsum) {
  __shared__ int s[256];
  int tid = threadIdx.x;
  int v = (tid < NBLK) ? bsum[tid] : 0;
  s[tid] = v;
  __syncthreads();
  for (int d = 1; d < 256; d <<= 1) {
    int t = (tid >= d) ? s[tid - d] : 0;
    __syncthreads();
    s[tid] += t;
    __syncthreads();
  }
  if (tid < NBLK) bsum[tid] = s[tid] - v;
}

__global__ void scan3_kernel(int* __restrict__ off, const int* __restrict__ bsum,
                             int* __restrict__ cursor) {
  int i = blockIdx.x * 256 + threadIdx.x;
  if (i < N_NODES) { int o = off[i] + bsum[blockIdx.x]; off[i] = o; cursor[i] = o; }
}

__global__ void dis_kernel(const int* __restrict__ deg, float* __restrict__ dis) {
  int n = blockIdx.x * blockDim.x + threadIdx.x;
  if (n < N_NODES) { int d = deg[n]; dis[n] = d > 0 ? rsqrtf((float)d) : 0.f; }
}

// scatter + meta fused: perm, rowP, nrmP in CSC order
__global__ void scatter2_kernel(const int* __restrict__ rowI, const int* __restrict__ colI,
                                const float* __restrict__ dis, int* __restrict__ cursor,
                                int* __restrict__ perm, int* __restrict__ rowP,
                                float* __restrict__ nrmP) {
  int e = blockIdx.x * blockDim.x + threadIdx.x;
  if (e < N_EDGES) {
    int c = colI[e], r = rowI[e];
    int p = atomicAdd(&cursor[c], 1);
    perm[p] = e;
    rowP[p] = r;
    nrmP[p] = dis[r] * dis[c];
  }
}

__global__ void permA_kernel(const float* __restrict__ attr, const int* __restrict__ perm,
                             unsigned short* __restrict__ attrP) {
  int t = blockIdx.x * 256 + threadIdx.x;  // E*16 threads, 4 channels each
  int i = t >> 4, q = t & 15;
  if (i >= N_EDGES) return;
  int e = perm[i];
  float4 v = *(const float4*)(attr + (size_t)e * 64 + q * 4);
  ushort4 o = {f2bf(v.x), f2bf(v.y), f2bf(v.z), f2bf(v.w)};
  *(ushort4*)(attrP + (size_t)i * 64 + q * 4) = o;
}

// ---- node GEMM K=128 (layer 0), streaming, bf16 out ----
__global__ __launch_bounds__(256, 4) void node_gemm128_kernel(
    const float* __restrict__ X, const float* __restrict__ W, const float* __restrict__ B,
    unsigned short* __restrict__ Y) {
  int row = blockIdx.x * 256 + threadIdx.x;
  int r = row < N_NODES ? row : N_NODES - 1;
  const float* xr = X + (long)r * 128;
  float acc[64];
#pragma unroll
  for (int c = 0; c < 64; ++c) acc[c] = B[c];
#pragma unroll 2
  for (int kb = 0; kb < 128; kb += 8) {
    float4 a0 = *(const float4*)(xr + kb);
    float4 a1 = *(const float4*)(xr + kb + 4);
    float av[8] = {a0.x, a0.y, a0.z, a0.w, a1.x, a1.y, a1.z, a1.w};
#pragma unroll
    for (int kk = 0; kk < 8; ++kk) {
      const float* wr = W + (kb + kk) * 64;
#pragma unroll
      for (int c = 0; c < 64; ++c) acc[c] = fmaf(av[kk], wr[c], acc[c]);
    }
  }
  if (row < N_NODES) {
    unsigned* yo = (unsigned*)(Y + (size_t)row * 64);
#pragma unroll
    for (int c = 0; c < 64; c += 2)
      yo[c >> 1] = (unsigned)f2bf(acc[c]) | ((unsigned)f2bf(acc[c + 1]) << 16);
  }
}

// ---- node GEMM K=64 with fused input ReLU+LayerNorm, bf16 out ----
__global__ __launch_bounds__(256, 3) void node_gemm64_kernel(
    const float* __restrict__ X, const float* __restrict__ W, const float* __restrict__ B,
    const float* __restrict__ G, const float* __restrict__ BT,
    unsigned short* __restrict__ Y) {
  int row = blockIdx.x * 256 + threadIdx.x;
  int r = row < N_NODES ? row : N_NODES - 1;
  const float* xr = X + (long)r * 64;
  float xv[64];
#pragma unroll
  for (int k = 0; k < 64; k += 4) {
    float4 v = *(const float4*)(xr + k);
    xv[k] = v.x; xv[k + 1] = v.y; xv[k + 2] = v.z; xv[k + 3] = v.w;
  }
  float mu = 0.f;
#pragma unroll
  for (int k = 0; k < 64; ++k) { xv[k] = fmaxf(xv[k], 0.f); mu += xv[k]; }
  mu *= (1.f / 64.f);
  float var = 0.f;
#pragma unroll
  for (int k = 0; k < 64; ++k) { float d = xv[k] - mu; var += d * d; }
  float is = rsqrtf(var * (1.f / 64.f) + LN_EPS);
#pragma unroll
  for (int k = 0; k < 64; ++k) xv[k] = (xv[k] - mu) * is * G[k] + BT[k];

  float acc[64];
#pragma unroll
  for (int c = 0; c < 64; ++c) acc[c] = B[c];
#pragma unroll 2
  for (int k = 0; k < 64; ++k) {
    const float* wr = W + k * 64;
#pragma unroll
    for (int c = 0; c < 64; ++c) acc[c] = fmaf(xv[k], wr[c], acc[c]);
  }
  if (row < N_NODES) {
    unsigned* yo = (unsigned*)(Y + (size_t)row * 64);
#pragma unroll
    for (int c = 0; c < 64; c += 2)
      yo[c >> 1] = (unsigned)f2bf(acc[c]) | ((unsigned)f2bf(acc[c + 1]) << 16);
  }
}

// ---- per-destination fused edge GEMM + aggregation (no atomics, no LDS) ----
// One wave owns 2 destination cols; in-edges contiguous in CSC order.
// MFMA: m = 16 edges, n = 64 channels (4 tiles), k = 64 (2 steps).
__global__ __launch_bounds__(256, 3) void edge_agg_kernel(
    const unsigned short* __restrict__ attrP, const int* __restrict__ rowP,
    const float* __restrict__ nrmP, const int* __restrict__ offB,
    const int* __restrict__ degI, const unsigned short* __restrict__ WcT,
    const float* __restrict__ bc, const unsigned short* __restrict__ XLb,
    float* __restrict__ OUT) {
  const int lane = threadIdx.x & 63;
  const int lr = lane & 15, lg = lane >> 4;
  const int gw = (blockIdx.x * 256 + threadIdx.x) >> 6;  // global wave id

  // B fragments (WcT[n][k], contiguous in k) + bias — loaded once, reused
  bf16x8 bfrag[4][2];
  float bias[4];
#pragma unroll
  for (int tn = 0; tn < 4; ++tn) {
    bias[tn] = bc[tn * 16 + lr];
#pragma unroll
    for (int kb = 0; kb < 2; ++kb)
      bfrag[tn][kb] = *(const bf16x8*)(WcT + (tn * 16 + lr) * 64 + kb * 32 + lg * 8);
  }

#pragma unroll 1
  for (int cc = 0; cc < 2; ++cc) {
    int c = gw * 2 + cc;
    if (c >= N_NODES) return;
    int off = offB[c], deg = degI[c];
    float fsum[4] = {0.f, 0.f, 0.f, 0.f};
#pragma unroll 1
    for (int b = 0; b < deg; b += 16) {
      int last = off + deg - 1;
      // A fragment: row = edge (lr), k-chunk = lg*8
      int ea = min(off + b + lr, last);
      const unsigned short* ap = attrP + (size_t)ea * 64 + lg * 8;
      bf16x8 a0 = *(const bf16x8*)(ap);
      bf16x8 a1 = *(const bf16x8*)(ap + 32);
      // per-edge meta for this lane's 4 output rows (edges b+lg*4+j)
      float nm[4]; int rj[4];
#pragma unroll
      for (int j = 0; j < 4; ++j) {
        int idx = b + lg * 4 + j;
        int e = min(off + idx, last);
        nm[j] = (idx < deg) ? nrmP[e] : 0.f;
        rj[j] = rowP[e];
      }
      // x gathers: 16 independent 2B loads, issued up front
      unsigned short xg[4][4];
#pragma unroll
      for (int j = 0; j < 4; ++j)
#pragma unroll
        for (int tn = 0; tn < 4; ++tn)
          xg[j][tn] = XLb[(size_t)rj[j] * 64 + tn * 16 + lr];
      // 8 MFMA back-to-back
      f32x4 acc[4];
#pragma unroll
      for (int tn = 0; tn < 4; ++tn) {
        f32x4 z = {0.f, 0.f, 0.f, 0.f};
        z = __builtin_amdgcn_mfma_f32_16x16x32_bf16(a0, bfrag[tn][0], z, 0, 0, 0);
        z = __builtin_amdgcn_mfma_f32_16x16x32_bf16(a1, bfrag[tn][1], z, 0, 0, 0);
        acc[tn] = z;
      }
      // epilogue: msg = (efl + bias) * nrm * x[row], accumulate
#pragma unroll
      for (int tn = 0; tn < 4; ++tn)
#pragma unroll
        for (int j = 0; j < 4; ++j)
          fsum[tn] += (acc[tn][j] + bias[tn]) * nm[j] * bf2f(xg[j][tn]);
    }
    // reduce over the 4 lane-groups (edges 0-3,4-7,8-11,12-15)
#pragma unroll
    for (int tn = 0; tn < 4; ++tn) {
      fsum[tn] += __shfl_xor(fsum[tn], 16);
      fsum[tn] += __shfl_xor(fsum[tn], 32);
    }
    if (lg == 0) {
#pragma unroll
      for (int tn = 0; tn < 4; ++tn)
        OUT[(size_t)c * 64 + tn * 16 + lr] = fsum[tn];
    }
  }
}

extern "C" void kernel_launch(void* const* d_in, const int* in_sizes, int n_in,
                              void* d_out, int out_size, void* d_ws, size_t ws_size,
                              hipStream_t stream) {
  const float* x    = (const float*)d_in[0];
  const int* eidx   = (const int*)d_in[1];
  const float* attr = (const float*)d_in[2];
  const float* We  = (const float*)d_in[3];
  const float* be  = (const float*)d_in[4];
  const float* W0  = (const float*)d_in[5];  const float* b0  = (const float*)d_in[6];
  const float* eW0 = (const float*)d_in[7];  const float* eb0 = (const float*)d_in[8];
  const float* W1  = (const float*)d_in[9];  const float* b1  = (const float*)d_in[10];
  const float* eW1 = (const float*)d_in[11]; const float* eb1 = (const float*)d_in[12];
  const float* W2  = (const float*)d_in[13]; const float* b2  = (const float*)d_in[14];
  const float* eW2 = (const float*)d_in[15]; const float* eb2 = (const float*)d_in[16];
  const float* g0  = (const float*)d_in[17]; const float* bt0 = (const float*)d_in[18];
  const float* g1  = (const float*)d_in[19]; const float* bt1 = (const float*)d_in[20];
  const int* rowI = eidx;
  const int* colI = eidx + N_EDGES;

  char* base = (char*)d_ws;
  size_t pos = 0;
  auto alloc = [&](size_t b) -> char* {
    char* p = base + pos;
    pos += (b + 255) & ~(size_t)255;
    return p;
  };
  unsigned short* XLb = (unsigned short*)alloc((size_t)N_NODES * 64 * 2);
  float* hB   = (float*)alloc((size_t)N_NODES * 64 * 4);
  float* nrmP = (float*)alloc((size_t)N_EDGES * 4);
  int* rowP   = (int*)alloc((size_t)N_EDGES * 4);
  int* perm   = (int*)alloc((size_t)N_EDGES * 4);
  int* degI   = (int*)alloc((size_t)N_NODES * 4);
  float* disF = (float*)alloc((size_t)N_NODES * 4);
  int* offB   = (int*)alloc((size_t)N_NODES * 4);
  int* curB   = (int*)alloc((size_t)N_NODES * 4);
  int* bsum   = (int*)alloc(256 * 4);
  unsigned short* WcT = (unsigned short*)alloc(3 * 4096 * 2);
  float* bcC  = (float*)alloc(3 * 64 * 4);
  unsigned short* attrP = (unsigned short*)alloc((size_t)N_EDGES * 64 * 2);
  (void)ws_size;
  float* out = (float*)d_out;

  // CSC build (sorted by destination col), fused meta
  hipMemsetAsync(degI, 0, (size_t)N_NODES * 4, stream);
  hist_kernel<<<N_EDGES / 256, 256, 0, stream>>>(colI, degI);
  scan1_kernel<<<NBLK, 256, 0, stream>>>(degI, offB, bsum);
  scan2_kernel<<<1, 256, 0, stream>>>(bsum);
  scan3_kernel<<<NBLK, 256, 0, stream>>>(offB, bsum, curB);
  dis_kernel<<<NBLK, 256, 0, stream>>>(degI, disF);
  scatter2_kernel<<<N_EDGES / 256, 256, 0, stream>>>(rowI, colI, disF, curB, perm, rowP, nrmP);
  permA_kernel<<<(N_EDGES * 16) / 256, 256, 0, stream>>>(attr, perm, attrP);
  wcomb_kernel<<<3, 256, 0, stream>>>(We, be, eW0, eb0, eW1, eb1, eW2, eb2, WcT, bcC);

  const int agg_grid = (N_NODES + 2 * 4 - 1) / (2 * 4);  // 2 cols/wave, 4 waves/block
  // layer 0
  node_gemm128_kernel<<<NBLK, 256, 0, stream>>>(x, W0, b0, XLb);
  edge_agg_kernel<<<agg_grid, 256, 0, stream>>>(attrP, rowP, nrmP, offB, degI, WcT, bcC, XLb, hB);
  // layer 1 (input ReLU+LN fused into node GEMM)
  node_gemm64_kernel<<<NBLK, 256, 0, stream>>>(hB, W1, b1, g0, bt0, XLb);
  edge_agg_kernel<<<agg_grid, 256, 0, stream>>>(attrP, rowP, nrmP, offB, degI, WcT + 4096, bcC + 64, XLb, hB);
  // layer 2
  node_gemm64_kernel<<<NBLK, 256, 0, stream>>>(hB, W2, b2, g1, bt1, XLb);
  edge_agg_kernel<<<agg_grid, 256, 0, stream>>>(attrP, rowP, nrmP, offB, degI, WcT + 8192, bcC + 128, XLb, out);
}